// Round 22
// baseline (84.522 us; speedup 1.0000x reference)
//
#include <hip/hip_runtime.h>
#include <math.h>

#define A_N   8732
#define C_N   81
#define B_N   32
#define NCLS  80
#define NTASK (B_N * NCLS)
#define TOPK  100
#define NTHR  256            // standalone-fallback block size
#define NTHS  128            // scatter block size: all 2208 blocks co-resident
#define NTHM  128            // main kernel block size
#define CAND  512
#define ACH   128                        // anchors per scatter chunk
#define NCH   ((A_N + ACH - 1) / ACH)    // 69
#define LCAP  16                         // LDS list slots per (block, task)
#define CPAD  16                         // gcount padding: 16 u32 = 64 B per task
#define THR_LOGIT (-0.8472978603872034)  // ln(3/7): sigmoid_f64(x)>0.3 <=> x>THR
#define XFIX  2.1f                       // optimistic gather threshold (mu~156)

// ---- LDS layout for main kernel: packed to 10.4 KB
#define OFF_SB0    0        // double[100] -> 800
#define OFF_SB1    800
#define OFF_SB2    1600
#define OFF_SB3    2400
#define OFF_SAREA  3200     // -> 4000
#define OFF_KEEPW  4000     // u64[2] -> 4016
#define OFF_HIST   0        // unsigned[1024] -> 4096 (fallback path only)
#define OFF_CAND   4096     // u64[512] -> 8192 (dead after rank)
#define OFF_FB0    4096     // float[100] (overlays cand, post-rank)
#define OFF_FB1    4496
#define OFF_FB2    4896
#define OFF_FB3    5296
#define OFF_FAREA  5696
#define OFF_FSC    6096
#define OFF_SVAL   6496     // int[100] -> 6896
#define OFF_SSEL   8192     // u64[100] -> 8992
#define OFF_SUP    8992     // u64[100][2] -> 10592
#define OFF_WT4    10592    // -> 10608
#define OFF_SCAL   10608    // -> 10616
#define SMEM_SZ    10624

__device__ __forceinline__ unsigned mapf(float x) {
    unsigned b = __float_as_uint(x);
    return b ^ ((b & 0x80000000u) ? 0xFFFFFFFFu : 0x80000000u);
}
__device__ __forceinline__ float unmapf(unsigned u) {
    unsigned b = (u & 0x80000000u) ? (u ^ 0x80000000u) : ~u;
    return __uint_as_float(b);
}

// Exact f64 decode (reference op order) from raw regression/prior values.
__device__ __forceinline__ void dec64(const float4 r4, const float4 p4,
                                      double* bx, double* area) {
    double ty = (double)r4.x / 10.0, tx = (double)r4.y / 10.0;
    double th = (double)r4.z / 5.0,  tw = (double)r4.w / 5.0;
    double cy = ty * (double)p4.z + (double)p4.x;
    double cx = tx * (double)p4.w + (double)p4.y;
    double hh = exp(th) * (double)p4.z;
    double ww = exp(tw) * (double)p4.w;
    bx[0] = cy - hh / 2.0; bx[1] = cx - ww / 2.0;
    bx[2] = cy + hh / 2.0; bx[3] = cx + ww / 2.0;
    double e0 = bx[2] - bx[0]; if (e0 < 0.0) e0 = 0.0;
    double e1 = bx[3] - bx[1]; if (e1 < 0.0) e1 = 0.0;
    *area = e0 * e1;
}

// ---- Kernel S: contiguous slab read + LDS-aggregated candidate scatter ----
// 128-thread blocks: 2208 blocks all co-resident (single flat round, no tail).
__global__ __launch_bounds__(NTHS) void scatter_cand_kernel(
    const float* __restrict__ logits,            // (B, A, 81)
    unsigned long long* __restrict__ gcand,      // (NTASK, CAND) full sort keys
    unsigned* __restrict__ gcountP)              // (NTASK * CPAD) padded counters
{
    __shared__ unsigned long long llist[NCLS * LCAP];   // 10 KB
    __shared__ unsigned lcnt[NCLS];
    __shared__ unsigned sbase[NCLS];

    const int b  = blockIdx.x / NCH;
    const int ck = blockIdx.x % NCH;
    const int a0 = ck * ACH;
    const int an = min(ACH, A_N - a0);
    const int tid = threadIdx.x;

    for (int i = tid; i < NCLS; i += NTHS) lcnt[i] = 0;
    __syncthreads();

    const unsigned NE4 = (unsigned)(an * C_N) / 4u;     // exact (NE % 4 == 0)
    const float4* src4 = (const float4*)logits
                       + ((size_t)C_N * ((size_t)b * A_N + a0)) / 4;

    auto PROC = [&](float4 v, unsigned f) {
        float mx = fmaxf(fmaxf(v.x, v.y), fmaxf(v.z, v.w));
        if (mx < XFIX) return;                          // ~93% of quads skip
        unsigned e = f * 4u;
        float xs[4] = { v.x, v.y, v.z, v.w };
        #pragma unroll
        for (int k = 0; k < 4; ++k) {
            if (xs[k] >= XFIX) {
                unsigned rel = e + (unsigned)k;
                unsigned ar = rel / (unsigned)C_N;      // const-div (magic mul)
                unsigned ch = rel - ar * (unsigned)C_N;
                if (ch > 0) {
                    int t = (int)ch - 1;
                    unsigned a = (unsigned)a0 + ar;
                    unsigned long long key =
                        ((unsigned long long)mapf(xs[k]) << 32) | (unsigned)(~a);
                    unsigned pos = atomicAdd(&lcnt[t], 1u);
                    if (pos < LCAP) {
                        llist[t * LCAP + pos] = key;
                    } else {                             // ~never: direct append
                        int task = b * NCLS + t;
                        unsigned p = atomicAdd(&gcountP[task * CPAD], 1u);
                        if (p < CAND) gcand[(size_t)task * CAND + p] = key;
                    }
                }
            }
        }
    };

    unsigned f = tid;
    for (; f + 7u * NTHS < NE4; f += 8u * NTHS) {       // 8 loads in flight
        float4 v0 = src4[f];
        float4 v1 = src4[f + NTHS];
        float4 v2 = src4[f + 2u * NTHS];
        float4 v3 = src4[f + 3u * NTHS];
        float4 v4 = src4[f + 4u * NTHS];
        float4 v5 = src4[f + 5u * NTHS];
        float4 v6 = src4[f + 6u * NTHS];
        float4 v7 = src4[f + 7u * NTHS];
        PROC(v0, f);               PROC(v1, f + NTHS);
        PROC(v2, f + 2u * NTHS);   PROC(v3, f + 3u * NTHS);
        PROC(v4, f + 4u * NTHS);   PROC(v5, f + 5u * NTHS);
        PROC(v6, f + 6u * NTHS);   PROC(v7, f + 7u * NTHS);
    }
    for (; f < NE4; f += NTHS) PROC(src4[f], f);
    __syncthreads();

    if (tid < NCLS) {
        unsigned n = lcnt[tid]; if (n > LCAP) n = LCAP;
        sbase[tid] = n ? atomicAdd(&gcountP[(b * NCLS + tid) * CPAD], n) : 0u;
        lcnt[tid] = n;
    }
    __syncthreads();

    for (int i = tid; i < NCLS * LCAP; i += NTHS) {
        int t = i >> 4, s = i & (LCAP - 1);
        if ((unsigned)s < lcnt[t]) {
            unsigned dst = sbase[t] + (unsigned)s;
            if (dst < CAND)
                gcand[(size_t)(b * NCLS + t) * CAND + dst] = llist[i];
        }
    }
}

// ---- Kernel M: one task per 128-thread block (R20/21-validated) ----
__global__ __launch_bounds__(NTHM) void ssd_nms_kernel(
    const float* __restrict__ logits,
    const unsigned long long* __restrict__ gcand,
    const unsigned* __restrict__ gcountP,
    const float* __restrict__ boxreg,
    const float* __restrict__ priors,
    float* __restrict__ out)
{
    const int task = blockIdx.x;
    const int b = task / NCLS;
    const int c = task % NCLS;
    const int tid = threadIdx.x;

    __shared__ __align__(16) char smem[SMEM_SZ];
    unsigned* hist = (unsigned*)(smem + OFF_HIST);
    unsigned long long* cand = (unsigned long long*)(smem + OFF_CAND);
    unsigned long long* ssel = (unsigned long long*)(smem + OFF_SSEL);
    unsigned* wt4 = (unsigned*)(smem + OFF_WT4);
    int* scal = (int*)(smem + OFF_SCAL);
    double* sb0 = (double*)(smem + OFF_SB0);
    double* sb1 = (double*)(smem + OFF_SB1);
    double* sb2 = (double*)(smem + OFF_SB2);
    double* sb3 = (double*)(smem + OFF_SB3);
    double* sarea = (double*)(smem + OFF_SAREA);
    float* fb0 = (float*)(smem + OFF_FB0);
    float* fb1 = (float*)(smem + OFF_FB1);
    float* fb2 = (float*)(smem + OFF_FB2);
    float* fb3 = (float*)(smem + OFF_FB3);
    float* farea = (float*)(smem + OFF_FAREA);
    float* fscore = (float*)(smem + OFF_FSC);
    int* svalid = (int*)(smem + OFF_SVAL);
    unsigned long long (*supmask)[2] = (unsigned long long (*)[2])(smem + OFF_SUP);
    unsigned long long* keepw = (unsigned long long*)(smem + OFF_KEEPW);

    const float* lg = logits + ((size_t)b * A_N * C_N) + (c + 1);

    if (tid < TOPK) ssel[tid] = 0ull;
    if (tid == 0) { scal[0] = 0; scal[1] = 1; }

    const int count = (int)gcountP[task * CPAD];
    int M;
    if (count >= TOPK && count <= CAND) {
        // optimistic: keys already assembled by the scatter kernel
        M = count;
        const unsigned long long* lst = gcand + (size_t)task * CAND;
        for (int i = tid; i < M; i += NTHM) cand[i] = lst[i];
    } else {
        // fallback: full strided scan (rare / degenerate data), 1024-bin hist
        for (int k = tid; k < 1024; k += NTHM) hist[k] = 0;
        __syncthreads();
        for (int a = tid; a < A_N; a += NTHM) {
            float x = lg[(size_t)a * C_N];
            if ((double)x > THR_LOGIT) atomicAdd(&hist[mapf(x) >> 22], 1u);
        }
        __syncthreads();
        {
            unsigned s = 0;
            #pragma unroll
            for (int k = 0; k < 8; ++k) s += hist[tid * 8 + k];
            unsigned incl = s;
            int lane = tid & 63;
            #pragma unroll
            for (int off = 1; off < 64; off <<= 1) {
                unsigned v = __shfl_down(incl, off);
                if (lane + off < 64) incl += v;
            }
            if (lane == 0) wt4[tid >> 6] = incl;     // waves 0,1
            __syncthreads();
            unsigned hi = (tid < 64) ? wt4[1] : 0u;  // waves above mine
            unsigned excl = hi + (incl - s);
            if (excl < TOPK && excl + s >= TOPK) {
                unsigned running = excl;
                #pragma unroll
                for (int k = 7; k >= 0; --k) {
                    running += hist[tid * 8 + k];
                    if (running >= TOPK) { scal[1] = (int)(((unsigned)(tid * 8 + k)) << 22); break; }
                }
            }
        }
        __syncthreads();
        const unsigned cutoff = (unsigned)scal[1];
        for (int a = tid; a < A_N; a += NTHM) {
            float x = lg[(size_t)a * C_N];
            if ((double)x > THR_LOGIT) {
                unsigned u = mapf(x);
                if (u >= cutoff) {
                    int p = atomicAdd(&scal[0], 1);
                    if (p < CAND) cand[p] = ((unsigned long long)u << 32) | (unsigned)(~(unsigned)a);
                }
            }
        }
        __syncthreads();
        M = min(scal[0], CAND);
    }
    {
        int Mr = (M + 7) & ~7;
        for (int i = M + tid; i < Mr; i += NTHM) cand[i] = 0ull;
    }
    __syncthreads();

    // ---- exact rank via all-pairs (order-independent, LDS broadcast reads)
    {
        int Mr = (M + 7) & ~7;
        for (int i = tid; i < Mr; i += NTHM) {
            unsigned long long mykey = cand[i];
            int rank = 0;
            #pragma unroll 8
            for (int j = 0; j < Mr; ++j) rank += (cand[j] > mykey) ? 1 : 0;
            if (mykey != 0ull && rank < TOPK) ssel[rank] = mykey;
        }
    }
    __syncthreads();

    // ---- decode top-100: f64 ONCE per box -> LDS; f32 shadows are casts
    if (tid < TOPK) {
        unsigned long long key = ssel[tid];
        int valid = (key != 0ull);
        double bx[4] = {0.0, 0.0, 0.0, 0.0}, ar = 0.0;
        float sc = 0.f;
        if (valid) {
            int a = (int)(~(unsigned)key);
            float x = unmapf((unsigned)(key >> 32));
            sc = 1.0f / (1.0f + __expf(-x));
            float4 r4 = *(const float4*)(boxreg + ((size_t)b * A_N + a) * 4);
            float4 p4 = *(const float4*)(priors + (size_t)a * 4);
            dec64(r4, p4, bx, &ar);
        }
        sb0[tid] = bx[0]; sb1[tid] = bx[1]; sb2[tid] = bx[2]; sb3[tid] = bx[3];
        sarea[tid] = ar;
        fb0[tid] = (float)bx[0]; fb1[tid] = (float)bx[1];
        fb2[tid] = (float)bx[2]; fb3[tid] = (float)bx[3];
        farea[tid] = (float)ar;
        fscore[tid] = sc;
        svalid[tid] = valid;
    }
    __syncthreads();

    // ---- suppression bitmask: f32 screen (narrow window), cheap f64 recheck
    for (int tt = tid; tt < 2 * TOPK; tt += NTHM) {
        int i = tt >> 1, w = tt & 1;
        unsigned long long m = 0;
        if (svalid[i]) {
            float i0 = fb0[i], i1 = fb1[i], i2 = fb2[i], i3 = fb3[i], ia = farea[i];
            int jbase = w * 64;
            int jend = min(jbase + 64, TOPK);
            int jstart = (jbase > i + 1) ? jbase : (i + 1);
            for (int j = jstart; j < jend; ++j) {
                float tl0 = fmaxf(i0, fb0[j]);
                float tl1 = fmaxf(i1, fb1[j]);
                float br0 = fminf(i2, fb2[j]);
                float br1 = fminf(i3, fb3[j]);
                float wh0 = fmaxf(br0 - tl0, 0.0f);
                float wh1 = fmaxf(br1 - tl1, 0.0f);
                float inter = wh0 * wh1;
                float denom = (ia + farea[j]) - inter;
                bool sup = inter > 0.6004f * denom;
                bool amb = !sup && (inter > 0.5996f * denom) && (inter > 0.0f);
                if (amb) {   // rare; cheap: f64 boxes already in LDS (no exp!)
                    double tl0d = fmax(sb0[i], sb0[j]);
                    double tl1d = fmax(sb1[i], sb1[j]);
                    double br0d = fmin(sb2[i], sb2[j]);
                    double br1d = fmin(sb3[i], sb3[j]);
                    double wh0d = br0d - tl0d; if (wh0d < 0.0) wh0d = 0.0;
                    double wh1d = br1d - tl1d; if (wh1d < 0.0) wh1d = 0.0;
                    double interd = wh0d * wh1d;
                    double denomd = ((sarea[i] + sarea[j]) - interd) + 1e-9;
                    sup = interd > 0.6 * denomd;
                }
                if (sup) m |= 1ull << (j - jbase);
            }
        }
        supmask[i][w] = m;
    }
    __syncthreads();

    // ---- serial greedy scan over bitmasks (tid 0; loads pipeline well)
    if (tid == 0) {
        unsigned long long kp0 = ~0ull, kp1 = ~0ull;
        for (int i = 0; i < TOPK; ++i) {
            bool kb = (i < 64) ? ((kp0 >> i) & 1ull) : ((kp1 >> (i - 64)) & 1ull);
            if (kb && svalid[i]) { kp0 &= ~supmask[i][0]; kp1 &= ~supmask[i][1]; }
        }
        keepw[0] = kp0; keepw[1] = kp1;
    }
    __syncthreads();

    // ---- write 5 floats per slot
    if (tid < TOPK) {
        bool kb = (tid < 64) ? ((keepw[0] >> tid) & 1ull)
                             : ((keepw[1] >> (tid - 64)) & 1ull);
        bool kp = kb && (svalid[tid] != 0);
        size_t base = ((size_t)task * TOPK + tid) * 5;
        out[base + 0] = kp ? fb0[tid] : 0.0f;
        out[base + 1] = kp ? fb1[tid] : 0.0f;
        out[base + 2] = kp ? fb2[tid] : 0.0f;
        out[base + 3] = kp ? fb3[tid] : 0.0f;
        out[base + 4] = kp ? fscore[tid] : 0.0f;
    }
}

// ---- Standalone fallback (ws too small): validated 256-thread path ----
__global__ __launch_bounds__(NTHR) void ssd_nms_fallback(
    const float* __restrict__ logits,
    const float* __restrict__ boxreg,
    const float* __restrict__ priors,
    float* __restrict__ out)
{
    const int task = blockIdx.x;
    const int b = task / NCLS;
    const int c = task % NCLS;
    const int tid = threadIdx.x;

    __shared__ unsigned hist[2048];
    __shared__ unsigned wt4[4];
    __shared__ unsigned long long cand[CAND];
    __shared__ unsigned long long ssel[TOPK];
    __shared__ double sb0[TOPK], sb1[TOPK], sb2[TOPK], sb3[TOPK], sarea[TOPK];
    __shared__ float fb0[TOPK], fb1[TOPK], fb2[TOPK], fb3[TOPK];
    __shared__ float farea[TOPK], fscore[TOPK];
    __shared__ int svalid[TOPK];
    __shared__ unsigned long long supmask[TOPK][2];
    __shared__ unsigned long long keepw[2];
    __shared__ int scal[2];

    const float* lg = logits + ((size_t)b * A_N * C_N) + (c + 1);

    for (int k = tid; k < 2048; k += NTHR) hist[k] = 0;
    for (int i = tid; i < CAND; i += NTHR) cand[i] = 0ull;
    if (tid < TOPK) ssel[tid] = 0ull;
    if (tid == 0) { scal[0] = 0; scal[1] = 1; }
    __syncthreads();

    for (int a = tid; a < A_N; a += NTHR) {
        float x = lg[(size_t)a * C_N];
        if ((double)x > THR_LOGIT) atomicAdd(&hist[mapf(x) >> 21], 1u);
    }
    __syncthreads();
    {
        unsigned s = 0;
        #pragma unroll
        for (int k = 0; k < 8; ++k) s += hist[tid * 8 + k];
        unsigned incl = s;
        int lane = tid & 63;
        #pragma unroll
        for (int off = 1; off < 64; off <<= 1) {
            unsigned v = __shfl_down(incl, off);
            if (lane + off < 64) incl += v;
        }
        if (lane == 0) wt4[tid >> 6] = incl;
        __syncthreads();
        unsigned hi = 0;
        #pragma unroll
        for (int w = 0; w < 4; ++w) if (w > (tid >> 6)) hi += wt4[w];
        unsigned excl = hi + (incl - s);
        if (excl < TOPK && excl + s >= TOPK) {
            unsigned running = excl;
            #pragma unroll
            for (int k = 7; k >= 0; --k) {
                running += hist[tid * 8 + k];
                if (running >= TOPK) { scal[1] = (int)(((unsigned)(tid * 8 + k)) << 21); break; }
            }
        }
    }
    __syncthreads();
    const unsigned cutoff = (unsigned)scal[1];

    for (int a = tid; a < A_N; a += NTHR) {
        float x = lg[(size_t)a * C_N];
        if ((double)x > THR_LOGIT) {
            unsigned u = mapf(x);
            if (u >= cutoff) {
                int p = atomicAdd(&scal[0], 1);
                if (p < CAND) cand[p] = ((unsigned long long)u << 32) | (unsigned)(~(unsigned)a);
            }
        }
    }
    __syncthreads();
    const int M = min(scal[0], CAND);
    {
        int Mr = (M + 7) & ~7;
        for (int i = tid; i < Mr; i += NTHR) {
            unsigned long long mykey = cand[i];
            int rank = 0;
            for (int j = 0; j < Mr; ++j) rank += (cand[j] > mykey) ? 1 : 0;
            if (mykey != 0ull && rank < TOPK) ssel[rank] = mykey;
        }
    }
    __syncthreads();
    if (tid < TOPK) {
        unsigned long long key = ssel[tid];
        int valid = (key != 0ull);
        double bx[4] = {0.0, 0.0, 0.0, 0.0}, ar = 0.0;
        float sc = 0.f;
        if (valid) {
            int a = (int)(~(unsigned)key);
            float x = unmapf((unsigned)(key >> 32));
            sc = 1.0f / (1.0f + __expf(-x));
            float4 r4 = *(const float4*)(boxreg + ((size_t)b * A_N + a) * 4);
            float4 p4 = *(const float4*)(priors + (size_t)a * 4);
            dec64(r4, p4, bx, &ar);
        }
        sb0[tid] = bx[0]; sb1[tid] = bx[1]; sb2[tid] = bx[2]; sb3[tid] = bx[3];
        sarea[tid] = ar;
        fb0[tid] = (float)bx[0]; fb1[tid] = (float)bx[1];
        fb2[tid] = (float)bx[2]; fb3[tid] = (float)bx[3];
        farea[tid] = (float)ar; fscore[tid] = sc; svalid[tid] = valid;
    }
    __syncthreads();
    if (tid < 2 * TOPK) {
        int i = tid >> 1, w = tid & 1;
        unsigned long long m = 0;
        if (svalid[i]) {
            float i0=fb0[i], i1=fb1[i], i2=fb2[i], i3=fb3[i], ia=farea[i];
            int jbase = w * 64, jend = min(jbase + 64, TOPK);
            int jstart = (jbase > i + 1) ? jbase : (i + 1);
            for (int j = jstart; j < jend; ++j) {
                float tl0=fmaxf(i0,fb0[j]), tl1=fmaxf(i1,fb1[j]);
                float br0=fminf(i2,fb2[j]), br1=fminf(i3,fb3[j]);
                float wh0=fmaxf(br0-tl0,0.f), wh1=fmaxf(br1-tl1,0.f);
                float inter=wh0*wh1, denom=(ia+farea[j])-inter;
                bool sup = inter > 0.6004f*denom;
                bool amb = !sup && (inter > 0.5996f*denom) && (inter > 0.f);
                if (amb) {
                    double tl0d = fmax(sb0[i], sb0[j]);
                    double tl1d = fmax(sb1[i], sb1[j]);
                    double br0d = fmin(sb2[i], sb2[j]);
                    double br1d = fmin(sb3[i], sb3[j]);
                    double wh0d = br0d - tl0d; if (wh0d < 0.0) wh0d = 0.0;
                    double wh1d = br1d - tl1d; if (wh1d < 0.0) wh1d = 0.0;
                    double interd = wh0d * wh1d;
                    sup = interd > 0.6 * (((sarea[i] + sarea[j]) - interd) + 1e-9);
                }
                if (sup) m |= 1ull << (j - jbase);
            }
        }
        supmask[i][w] = m;
    }
    __syncthreads();
    if (tid == 0) {
        unsigned long long kp0 = ~0ull, kp1 = ~0ull;
        for (int i = 0; i < TOPK; ++i) {
            bool kb = (i < 64) ? ((kp0 >> i) & 1ull) : ((kp1 >> (i - 64)) & 1ull);
            if (kb && svalid[i]) { kp0 &= ~supmask[i][0]; kp1 &= ~supmask[i][1]; }
        }
        keepw[0] = kp0; keepw[1] = kp1;
    }
    __syncthreads();
    if (tid < TOPK) {
        bool kb = (tid < 64) ? ((keepw[0] >> tid) & 1ull)
                             : ((keepw[1] >> (tid - 64)) & 1ull);
        bool kp = kb && (svalid[tid] != 0);
        size_t base = ((size_t)task * TOPK + tid) * 5;
        out[base + 0] = kp ? fb0[tid] : 0.0f;
        out[base + 1] = kp ? fb1[tid] : 0.0f;
        out[base + 2] = kp ? fb2[tid] : 0.0f;
        out[base + 3] = kp ? fb3[tid] : 0.0f;
        out[base + 4] = kp ? fscore[tid] : 0.0f;
    }
}

extern "C" void kernel_launch(void* const* d_in, const int* in_sizes, int n_in,
                              void* d_out, int out_size, void* d_ws, size_t ws_size,
                              hipStream_t stream) {
    const float* logits = (const float*)d_in[0];
    const float* boxreg = (const float*)d_in[1];
    const float* priors = (const float*)d_in[2];
    float* out = (float*)d_out;

    const size_t cand_bytes  = (size_t)NTASK * CAND * sizeof(unsigned long long); // 10.49 MB
    const size_t count_bytes = (size_t)NTASK * CPAD * sizeof(unsigned);           // 160 KB
    if (ws_size >= cand_bytes + count_bytes) {
        unsigned long long* gcand = (unsigned long long*)d_ws;
        unsigned* gcountP = (unsigned*)((char*)d_ws + cand_bytes);
        hipMemsetAsync(gcountP, 0, count_bytes, stream);
        scatter_cand_kernel<<<dim3(B_N * NCH), dim3(NTHS), 0, stream>>>(
            logits, gcand, gcountP);
        ssd_nms_kernel<<<dim3(NTASK), dim3(NTHM), 0, stream>>>(
            logits, gcand, gcountP, boxreg, priors, out);
    } else {
        ssd_nms_fallback<<<dim3(NTASK), dim3(NTHR), 0, stream>>>(
            logits, boxreg, priors, out);
    }
}

// Round 23
// 81.557 us; speedup vs baseline: 1.0364x; 1.0364x over previous
//
#include <hip/hip_runtime.h>
#include <math.h>

#define A_N   8732
#define C_N   81
#define B_N   32
#define NCLS  80
#define NTASK (B_N * NCLS)
#define TOPK  100
#define NTHR  256            // scatter / standalone-fallback block size
#define NTHM  128            // main kernel block size
#define CAND  512
#define ACH   128                        // anchors per scatter chunk
#define NCH   ((A_N + ACH - 1) / ACH)    // 69
#define LCAP  16                         // LDS list slots per (block, task)
#define CPAD  16                         // gcount padding: 16 u32 = 64 B per task
#define THR_LOGIT (-0.8472978603872034)  // ln(3/7): sigmoid_f64(x)>0.3 <=> x>THR
#define XFIX  2.1f                       // optimistic gather threshold (mu~156)

// ---- LDS layout for main kernel: packed to 10.4 KB
#define OFF_SB0    0        // double[100] -> 800
#define OFF_SB1    800
#define OFF_SB2    1600
#define OFF_SB3    2400
#define OFF_SAREA  3200     // -> 4000
#define OFF_KEEPW  4000     // u64[2] -> 4016
#define OFF_HIST   0        // unsigned[1024] -> 4096 (fallback path only)
#define OFF_CAND   4096     // u64[512] -> 8192 (dead after rank)
#define OFF_FB0    4096     // float[100] (overlays cand, post-rank)
#define OFF_FB1    4496
#define OFF_FB2    4896
#define OFF_FB3    5296
#define OFF_FAREA  5696
#define OFF_FSC    6096
#define OFF_SVAL   6496     // int[100] -> 6896
#define OFF_SSEL   8192     // u64[100] -> 8992
#define OFF_SUP    8992     // u64[100][2] -> 10592
#define OFF_WT4    10592    // -> 10608
#define OFF_SCAL   10608    // -> 10616
#define SMEM_SZ    10624

__device__ __forceinline__ unsigned mapf(float x) {
    unsigned b = __float_as_uint(x);
    return b ^ ((b & 0x80000000u) ? 0xFFFFFFFFu : 0x80000000u);
}
__device__ __forceinline__ float unmapf(unsigned u) {
    unsigned b = (u & 0x80000000u) ? (u ^ 0x80000000u) : ~u;
    return __uint_as_float(b);
}

// Exact f64 decode (reference op order) from raw regression/prior values.
__device__ __forceinline__ void dec64(const float4 r4, const float4 p4,
                                      double* bx, double* area) {
    double ty = (double)r4.x / 10.0, tx = (double)r4.y / 10.0;
    double th = (double)r4.z / 5.0,  tw = (double)r4.w / 5.0;
    double cy = ty * (double)p4.z + (double)p4.x;
    double cx = tx * (double)p4.w + (double)p4.y;
    double hh = exp(th) * (double)p4.z;
    double ww = exp(tw) * (double)p4.w;
    bx[0] = cy - hh / 2.0; bx[1] = cx - ww / 2.0;
    bx[2] = cy + hh / 2.0; bx[3] = cx + ww / 2.0;
    double e0 = bx[2] - bx[0]; if (e0 < 0.0) e0 = 0.0;
    double e1 = bx[3] - bx[1]; if (e1 < 0.0) e1 = 0.0;
    *area = e0 * e1;
}

// ---- Kernel S: contiguous slab read + LDS-aggregated candidate scatter ----
__global__ __launch_bounds__(NTHR) void scatter_cand_kernel(
    const float* __restrict__ logits,            // (B, A, 81)
    unsigned long long* __restrict__ gcand,      // (NTASK, CAND) full sort keys
    unsigned* __restrict__ gcountP)              // (NTASK * CPAD) padded counters
{
    __shared__ unsigned long long llist[NCLS * LCAP];   // 10 KB
    __shared__ unsigned lcnt[NCLS];
    __shared__ unsigned sbase[NCLS];

    const int b  = blockIdx.x / NCH;
    const int ck = blockIdx.x % NCH;
    const int a0 = ck * ACH;
    const int an = min(ACH, A_N - a0);
    const int tid = threadIdx.x;

    for (int i = tid; i < NCLS; i += NTHR) lcnt[i] = 0;
    __syncthreads();

    const unsigned NE4 = (unsigned)(an * C_N) / 4u;     // exact (NE % 4 == 0)
    const float4* src4 = (const float4*)logits
                       + ((size_t)C_N * ((size_t)b * A_N + a0)) / 4;

    auto PROC = [&](float4 v, unsigned f) {
        float mx = fmaxf(fmaxf(v.x, v.y), fmaxf(v.z, v.w));
        if (mx < XFIX) return;                          // ~93% of quads skip
        unsigned e = f * 4u;
        float xs[4] = { v.x, v.y, v.z, v.w };
        #pragma unroll
        for (int k = 0; k < 4; ++k) {
            if (xs[k] >= XFIX) {
                unsigned rel = e + (unsigned)k;
                unsigned ar = rel / (unsigned)C_N;      // const-div (magic mul)
                unsigned ch = rel - ar * (unsigned)C_N;
                if (ch > 0) {
                    int t = (int)ch - 1;
                    unsigned a = (unsigned)a0 + ar;
                    unsigned long long key =
                        ((unsigned long long)mapf(xs[k]) << 32) | (unsigned)(~a);
                    unsigned pos = atomicAdd(&lcnt[t], 1u);
                    if (pos < LCAP) {
                        llist[t * LCAP + pos] = key;
                    } else {                             // ~never: direct append
                        int task = b * NCLS + t;
                        unsigned p = atomicAdd(&gcountP[task * CPAD], 1u);
                        if (p < CAND) gcand[(size_t)task * CAND + p] = key;
                    }
                }
            }
        }
    };

    unsigned f = tid;
    for (; f + 7u * NTHR < NE4; f += 8u * NTHR) {       // 8 loads in flight
        float4 v0 = src4[f];
        float4 v1 = src4[f + NTHR];
        float4 v2 = src4[f + 2u * NTHR];
        float4 v3 = src4[f + 3u * NTHR];
        float4 v4 = src4[f + 4u * NTHR];
        float4 v5 = src4[f + 5u * NTHR];
        float4 v6 = src4[f + 6u * NTHR];
        float4 v7 = src4[f + 7u * NTHR];
        PROC(v0, f);               PROC(v1, f + NTHR);
        PROC(v2, f + 2u * NTHR);   PROC(v3, f + 3u * NTHR);
        PROC(v4, f + 4u * NTHR);   PROC(v5, f + 5u * NTHR);
        PROC(v6, f + 6u * NTHR);   PROC(v7, f + 7u * NTHR);
    }
    for (; f < NE4; f += NTHR) PROC(src4[f], f);
    __syncthreads();

    if (tid < NCLS) {
        unsigned n = lcnt[tid]; if (n > LCAP) n = LCAP;
        sbase[tid] = n ? atomicAdd(&gcountP[(b * NCLS + tid) * CPAD], n) : 0u;
        lcnt[tid] = n;
    }
    __syncthreads();

    for (int i = tid; i < NCLS * LCAP; i += NTHR) {
        int t = i >> 4, s = i & (LCAP - 1);
        if ((unsigned)s < lcnt[t]) {
            unsigned dst = sbase[t] + (unsigned)s;
            if (dst < CAND)
                gcand[(size_t)(b * NCLS + t) * CAND + dst] = llist[i];
        }
    }
}

// ---- Kernel M: one task per 128-thread block ----
__global__ __launch_bounds__(NTHM) void ssd_nms_kernel(
    const float* __restrict__ logits,
    const unsigned long long* __restrict__ gcand,
    const unsigned* __restrict__ gcountP,
    const float* __restrict__ boxreg,
    const float* __restrict__ priors,
    float* __restrict__ out)
{
    const int task = blockIdx.x;
    const int b = task / NCLS;
    const int c = task % NCLS;
    const int tid = threadIdx.x;

    __shared__ __align__(16) char smem[SMEM_SZ];
    unsigned* hist = (unsigned*)(smem + OFF_HIST);
    unsigned long long* cand = (unsigned long long*)(smem + OFF_CAND);
    unsigned long long* ssel = (unsigned long long*)(smem + OFF_SSEL);
    unsigned* wt4 = (unsigned*)(smem + OFF_WT4);
    int* scal = (int*)(smem + OFF_SCAL);
    double* sb0 = (double*)(smem + OFF_SB0);
    double* sb1 = (double*)(smem + OFF_SB1);
    double* sb2 = (double*)(smem + OFF_SB2);
    double* sb3 = (double*)(smem + OFF_SB3);
    double* sarea = (double*)(smem + OFF_SAREA);
    float* fb0 = (float*)(smem + OFF_FB0);
    float* fb1 = (float*)(smem + OFF_FB1);
    float* fb2 = (float*)(smem + OFF_FB2);
    float* fb3 = (float*)(smem + OFF_FB3);
    float* farea = (float*)(smem + OFF_FAREA);
    float* fscore = (float*)(smem + OFF_FSC);
    int* svalid = (int*)(smem + OFF_SVAL);
    unsigned long long (*supmask)[2] = (unsigned long long (*)[2])(smem + OFF_SUP);
    unsigned long long* keepw = (unsigned long long*)(smem + OFF_KEEPW);

    const float* lg = logits + ((size_t)b * A_N * C_N) + (c + 1);

    if (tid < TOPK) ssel[tid] = 0ull;
    if (tid == 0) { scal[0] = 0; scal[1] = 1; }

    const int count = (int)gcountP[task * CPAD];
    int M;
    if (count >= TOPK && count <= CAND) {
        // optimistic: keys already assembled by the scatter kernel
        M = count;
        const unsigned long long* lst = gcand + (size_t)task * CAND;
        for (int i = tid; i < M; i += NTHM) cand[i] = lst[i];
    } else {
        // fallback: full strided scan (rare / degenerate data), 1024-bin hist
        for (int k = tid; k < 1024; k += NTHM) hist[k] = 0;
        __syncthreads();
        for (int a = tid; a < A_N; a += NTHM) {
            float x = lg[(size_t)a * C_N];
            if ((double)x > THR_LOGIT) atomicAdd(&hist[mapf(x) >> 22], 1u);
        }
        __syncthreads();
        {
            unsigned s = 0;
            #pragma unroll
            for (int k = 0; k < 8; ++k) s += hist[tid * 8 + k];
            unsigned incl = s;
            int lane = tid & 63;
            #pragma unroll
            for (int off = 1; off < 64; off <<= 1) {
                unsigned v = __shfl_down(incl, off);
                if (lane + off < 64) incl += v;
            }
            if (lane == 0) wt4[tid >> 6] = incl;     // waves 0,1
            __syncthreads();
            unsigned hi = (tid < 64) ? wt4[1] : 0u;  // waves above mine
            unsigned excl = hi + (incl - s);
            if (excl < TOPK && excl + s >= TOPK) {
                unsigned running = excl;
                #pragma unroll
                for (int k = 7; k >= 0; --k) {
                    running += hist[tid * 8 + k];
                    if (running >= TOPK) { scal[1] = (int)(((unsigned)(tid * 8 + k)) << 22); break; }
                }
            }
        }
        __syncthreads();
        const unsigned cutoff = (unsigned)scal[1];
        for (int a = tid; a < A_N; a += NTHM) {
            float x = lg[(size_t)a * C_N];
            if ((double)x > THR_LOGIT) {
                unsigned u = mapf(x);
                if (u >= cutoff) {
                    int p = atomicAdd(&scal[0], 1);
                    if (p < CAND) cand[p] = ((unsigned long long)u << 32) | (unsigned)(~(unsigned)a);
                }
            }
        }
        __syncthreads();
        M = min(scal[0], CAND);
    }
    {
        int Mr = (M + 7) & ~7;
        for (int i = M + tid; i < Mr; i += NTHM) cand[i] = 0ull;
    }
    __syncthreads();

    // ---- exact rank via all-pairs (order-independent, LDS broadcast reads)
    {
        int Mr = (M + 7) & ~7;
        for (int i = tid; i < Mr; i += NTHM) {
            unsigned long long mykey = cand[i];
            int rank = 0;
            #pragma unroll 8
            for (int j = 0; j < Mr; ++j) rank += (cand[j] > mykey) ? 1 : 0;
            if (mykey != 0ull && rank < TOPK) ssel[rank] = mykey;
        }
    }
    __syncthreads();

    // ---- decode top-100: f64 ONCE per box -> LDS; f32 shadows are casts
    if (tid < TOPK) {
        unsigned long long key = ssel[tid];
        int valid = (key != 0ull);
        double bx[4] = {0.0, 0.0, 0.0, 0.0}, ar = 0.0;
        float sc = 0.f;
        if (valid) {
            int a = (int)(~(unsigned)key);
            float x = unmapf((unsigned)(key >> 32));
            sc = 1.0f / (1.0f + __expf(-x));
            float4 r4 = *(const float4*)(boxreg + ((size_t)b * A_N + a) * 4);
            float4 p4 = *(const float4*)(priors + (size_t)a * 4);
            dec64(r4, p4, bx, &ar);
        }
        sb0[tid] = bx[0]; sb1[tid] = bx[1]; sb2[tid] = bx[2]; sb3[tid] = bx[3];
        sarea[tid] = ar;
        fb0[tid] = (float)bx[0]; fb1[tid] = (float)bx[1];
        fb2[tid] = (float)bx[2]; fb3[tid] = (float)bx[3];
        farea[tid] = (float)ar;
        fscore[tid] = sc;
        svalid[tid] = valid;
    }
    __syncthreads();

    // ---- suppression bitmask: f32 screen (narrow window), cheap f64 recheck
    for (int tt = tid; tt < 2 * TOPK; tt += NTHM) {
        int i = tt >> 1, w = tt & 1;
        unsigned long long m = 0;
        if (svalid[i]) {
            float i0 = fb0[i], i1 = fb1[i], i2 = fb2[i], i3 = fb3[i], ia = farea[i];
            int jbase = w * 64;
            int jend = min(jbase + 64, TOPK);
            int jstart = (jbase > i + 1) ? jbase : (i + 1);
            for (int j = jstart; j < jend; ++j) {
                float tl0 = fmaxf(i0, fb0[j]);
                float tl1 = fmaxf(i1, fb1[j]);
                float br0 = fminf(i2, fb2[j]);
                float br1 = fminf(i3, fb3[j]);
                float wh0 = fmaxf(br0 - tl0, 0.0f);
                float wh1 = fmaxf(br1 - tl1, 0.0f);
                float inter = wh0 * wh1;
                float denom = (ia + farea[j]) - inter;
                bool sup = inter > 0.6004f * denom;
                bool amb = !sup && (inter > 0.5996f * denom) && (inter > 0.0f);
                if (amb) {   // rare; cheap: f64 boxes already in LDS (no exp!)
                    double tl0d = fmax(sb0[i], sb0[j]);
                    double tl1d = fmax(sb1[i], sb1[j]);
                    double br0d = fmin(sb2[i], sb2[j]);
                    double br1d = fmin(sb3[i], sb3[j]);
                    double wh0d = br0d - tl0d; if (wh0d < 0.0) wh0d = 0.0;
                    double wh1d = br1d - tl1d; if (wh1d < 0.0) wh1d = 0.0;
                    double interd = wh0d * wh1d;
                    double denomd = ((sarea[i] + sarea[j]) - interd) + 1e-9;
                    sup = interd > 0.6 * denomd;
                }
                if (sup) m |= 1ull << (j - jbase);
            }
        }
        supmask[i][w] = m;
    }
    __syncthreads();

    // ---- serial greedy scan over bitmasks (tid 0; loads pipeline well)
    if (tid == 0) {
        unsigned long long kp0 = ~0ull, kp1 = ~0ull;
        for (int i = 0; i < TOPK; ++i) {
            bool kb = (i < 64) ? ((kp0 >> i) & 1ull) : ((kp1 >> (i - 64)) & 1ull);
            if (kb && svalid[i]) { kp0 &= ~supmask[i][0]; kp1 &= ~supmask[i][1]; }
        }
        keepw[0] = kp0; keepw[1] = kp1;
    }
    __syncthreads();

    // ---- write 5 floats per slot
    if (tid < TOPK) {
        bool kb = (tid < 64) ? ((keepw[0] >> tid) & 1ull)
                             : ((keepw[1] >> (tid - 64)) & 1ull);
        bool kp = kb && (svalid[tid] != 0);
        size_t base = ((size_t)task * TOPK + tid) * 5;
        out[base + 0] = kp ? fb0[tid] : 0.0f;
        out[base + 1] = kp ? fb1[tid] : 0.0f;
        out[base + 2] = kp ? fb2[tid] : 0.0f;
        out[base + 3] = kp ? fb3[tid] : 0.0f;
        out[base + 4] = kp ? fscore[tid] : 0.0f;
    }
}

// ---- Standalone fallback (ws too small): validated 256-thread path ----
__global__ __launch_bounds__(NTHR) void ssd_nms_fallback(
    const float* __restrict__ logits,
    const float* __restrict__ boxreg,
    const float* __restrict__ priors,
    float* __restrict__ out)
{
    const int task = blockIdx.x;
    const int b = task / NCLS;
    const int c = task % NCLS;
    const int tid = threadIdx.x;

    __shared__ unsigned hist[2048];
    __shared__ unsigned wt4[4];
    __shared__ unsigned long long cand[CAND];
    __shared__ unsigned long long ssel[TOPK];
    __shared__ double sb0[TOPK], sb1[TOPK], sb2[TOPK], sb3[TOPK], sarea[TOPK];
    __shared__ float fb0[TOPK], fb1[TOPK], fb2[TOPK], fb3[TOPK];
    __shared__ float farea[TOPK], fscore[TOPK];
    __shared__ int svalid[TOPK];
    __shared__ unsigned long long supmask[TOPK][2];
    __shared__ unsigned long long keepw[2];
    __shared__ int scal[2];

    const float* lg = logits + ((size_t)b * A_N * C_N) + (c + 1);

    for (int k = tid; k < 2048; k += NTHR) hist[k] = 0;
    for (int i = tid; i < CAND; i += NTHR) cand[i] = 0ull;
    if (tid < TOPK) ssel[tid] = 0ull;
    if (tid == 0) { scal[0] = 0; scal[1] = 1; }
    __syncthreads();

    for (int a = tid; a < A_N; a += NTHR) {
        float x = lg[(size_t)a * C_N];
        if ((double)x > THR_LOGIT) atomicAdd(&hist[mapf(x) >> 21], 1u);
    }
    __syncthreads();
    {
        unsigned s = 0;
        #pragma unroll
        for (int k = 0; k < 8; ++k) s += hist[tid * 8 + k];
        unsigned incl = s;
        int lane = tid & 63;
        #pragma unroll
        for (int off = 1; off < 64; off <<= 1) {
            unsigned v = __shfl_down(incl, off);
            if (lane + off < 64) incl += v;
        }
        if (lane == 0) wt4[tid >> 6] = incl;
        __syncthreads();
        unsigned hi = 0;
        #pragma unroll
        for (int w = 0; w < 4; ++w) if (w > (tid >> 6)) hi += wt4[w];
        unsigned excl = hi + (incl - s);
        if (excl < TOPK && excl + s >= TOPK) {
            unsigned running = excl;
            #pragma unroll
            for (int k = 7; k >= 0; --k) {
                running += hist[tid * 8 + k];
                if (running >= TOPK) { scal[1] = (int)(((unsigned)(tid * 8 + k)) << 21); break; }
            }
        }
    }
    __syncthreads();
    const unsigned cutoff = (unsigned)scal[1];

    for (int a = tid; a < A_N; a += NTHR) {
        float x = lg[(size_t)a * C_N];
        if ((double)x > THR_LOGIT) {
            unsigned u = mapf(x);
            if (u >= cutoff) {
                int p = atomicAdd(&scal[0], 1);
                if (p < CAND) cand[p] = ((unsigned long long)u << 32) | (unsigned)(~(unsigned)a);
            }
        }
    }
    __syncthreads();
    const int M = min(scal[0], CAND);
    {
        int Mr = (M + 7) & ~7;
        for (int i = tid; i < Mr; i += NTHR) {
            unsigned long long mykey = cand[i];
            int rank = 0;
            for (int j = 0; j < Mr; ++j) rank += (cand[j] > mykey) ? 1 : 0;
            if (mykey != 0ull && rank < TOPK) ssel[rank] = mykey;
        }
    }
    __syncthreads();
    if (tid < TOPK) {
        unsigned long long key = ssel[tid];
        int valid = (key != 0ull);
        double bx[4] = {0.0, 0.0, 0.0, 0.0}, ar = 0.0;
        float sc = 0.f;
        if (valid) {
            int a = (int)(~(unsigned)key);
            float x = unmapf((unsigned)(key >> 32));
            sc = 1.0f / (1.0f + __expf(-x));
            float4 r4 = *(const float4*)(boxreg + ((size_t)b * A_N + a) * 4);
            float4 p4 = *(const float4*)(priors + (size_t)a * 4);
            dec64(r4, p4, bx, &ar);
        }
        sb0[tid] = bx[0]; sb1[tid] = bx[1]; sb2[tid] = bx[2]; sb3[tid] = bx[3];
        sarea[tid] = ar;
        fb0[tid] = (float)bx[0]; fb1[tid] = (float)bx[1];
        fb2[tid] = (float)bx[2]; fb3[tid] = (float)bx[3];
        farea[tid] = (float)ar; fscore[tid] = sc; svalid[tid] = valid;
    }
    __syncthreads();
    if (tid < 2 * TOPK) {
        int i = tid >> 1, w = tid & 1;
        unsigned long long m = 0;
        if (svalid[i]) {
            float i0=fb0[i], i1=fb1[i], i2=fb2[i], i3=fb3[i], ia=farea[i];
            int jbase = w * 64, jend = min(jbase + 64, TOPK);
            int jstart = (jbase > i + 1) ? jbase : (i + 1);
            for (int j = jstart; j < jend; ++j) {
                float tl0=fmaxf(i0,fb0[j]), tl1=fmaxf(i1,fb1[j]);
                float br0=fminf(i2,fb2[j]), br1=fminf(i3,fb3[j]);
                float wh0=fmaxf(br0-tl0,0.f), wh1=fmaxf(br1-tl1,0.f);
                float inter=wh0*wh1, denom=(ia+farea[j])-inter;
                bool sup = inter > 0.6004f*denom;
                bool amb = !sup && (inter > 0.5996f*denom) && (inter > 0.f);
                if (amb) {
                    double tl0d = fmax(sb0[i], sb0[j]);
                    double tl1d = fmax(sb1[i], sb1[j]);
                    double br0d = fmin(sb2[i], sb2[j]);
                    double br1d = fmin(sb3[i], sb3[j]);
                    double wh0d = br0d - tl0d; if (wh0d < 0.0) wh0d = 0.0;
                    double wh1d = br1d - tl1d; if (wh1d < 0.0) wh1d = 0.0;
                    double interd = wh0d * wh1d;
                    sup = interd > 0.6 * (((sarea[i] + sarea[j]) - interd) + 1e-9);
                }
                if (sup) m |= 1ull << (j - jbase);
            }
        }
        supmask[i][w] = m;
    }
    __syncthreads();
    if (tid == 0) {
        unsigned long long kp0 = ~0ull, kp1 = ~0ull;
        for (int i = 0; i < TOPK; ++i) {
            bool kb = (i < 64) ? ((kp0 >> i) & 1ull) : ((kp1 >> (i - 64)) & 1ull);
            if (kb && svalid[i]) { kp0 &= ~supmask[i][0]; kp1 &= ~supmask[i][1]; }
        }
        keepw[0] = kp0; keepw[1] = kp1;
    }
    __syncthreads();
    if (tid < TOPK) {
        bool kb = (tid < 64) ? ((keepw[0] >> tid) & 1ull)
                             : ((keepw[1] >> (tid - 64)) & 1ull);
        bool kp = kb && (svalid[tid] != 0);
        size_t base = ((size_t)task * TOPK + tid) * 5;
        out[base + 0] = kp ? fb0[tid] : 0.0f;
        out[base + 1] = kp ? fb1[tid] : 0.0f;
        out[base + 2] = kp ? fb2[tid] : 0.0f;
        out[base + 3] = kp ? fb3[tid] : 0.0f;
        out[base + 4] = kp ? fscore[tid] : 0.0f;
    }
}

extern "C" void kernel_launch(void* const* d_in, const int* in_sizes, int n_in,
                              void* d_out, int out_size, void* d_ws, size_t ws_size,
                              hipStream_t stream) {
    const float* logits = (const float*)d_in[0];
    const float* boxreg = (const float*)d_in[1];
    const float* priors = (const float*)d_in[2];
    float* out = (float*)d_out;

    const size_t cand_bytes  = (size_t)NTASK * CAND * sizeof(unsigned long long); // 10.49 MB
    const size_t count_bytes = (size_t)NTASK * CPAD * sizeof(unsigned);           // 160 KB
    if (ws_size >= cand_bytes + count_bytes) {
        unsigned long long* gcand = (unsigned long long*)d_ws;
        unsigned* gcountP = (unsigned*)((char*)d_ws + cand_bytes);
        hipMemsetAsync(gcountP, 0, count_bytes, stream);
        scatter_cand_kernel<<<dim3(B_N * NCH), dim3(NTHR), 0, stream>>>(
            logits, gcand, gcountP);
        ssd_nms_kernel<<<dim3(NTASK), dim3(NTHM), 0, stream>>>(
            logits, gcand, gcountP, boxreg, priors, out);
    } else {
        ssd_nms_fallback<<<dim3(NTASK), dim3(NTHR), 0, stream>>>(
            logits, boxreg, priors, out);
    }
}